// Round 3
// baseline (538.152 us; speedup 1.0000x reference)
//
#include <hip/hip_runtime.h>

static constexpr int NB   = 128;
static constexpr int NCIN = 64;
static constexpr int NG   = 8;
static constexpr int NH   = 14;
static constexpr int NP   = 16;
static constexpr int HH   = NH * NH;   // 196
static constexpr int LROW = 20;        // padded t4 LDS row: l in [-2,17]

// ---------------------------------------------------------------------------
// Kernel 1: channel mix. t4[bg][s][p] = sum_cin x[b][cin][g][s] * wmix[cin][p]
// One spatial position per thread: wave = 64 consecutive s -> 256B coalesced
// dword loads; wmix addresses are thread-uniform -> scalar loads.
// 200704 threads = 784 blocks x 256.
// ---------------------------------------------------------------------------
__global__ __launch_bounds__(256, 4) void mix_kernel(const float* __restrict__ x,
                                                     const float* __restrict__ wmix,
                                                     float* __restrict__ t4) {
    int t  = blockIdx.x * 256 + threadIdx.x;   // enumerates (bg, s)
    int bg = t / HH;
    int s  = t % HH;

    float acc[NP];
#pragma unroll
    for (int p = 0; p < NP; p++) acc[p] = 0.f;

    const float* xb = x + (size_t)(bg >> 3) * (NCIN * NG * HH)
                        + (size_t)(bg & 7) * HH + s;

#pragma unroll 8
    for (int cin = 0; cin < NCIN; cin++) {
        float xv = xb[(size_t)cin * (NG * HH)];
#pragma unroll
        for (int p = 0; p < NP; p++) acc[p] += xv * wmix[cin * NP + p];
    }

    float* tb = t4 + (size_t)t * NP;           // (bg*196+s)*16
#pragma unroll
    for (int q = 0; q < 4; q++)
        *reinterpret_cast<float4*>(tb + q * 4) =
            make_float4(acc[q * 4 + 0], acc[q * 4 + 1], acc[q * 4 + 2], acc[q * 4 + 3]);
}

// ---------------------------------------------------------------------------
// Kernel 2: 5-tap conv along l + boundary corrections + roll + transpose.
// block = (b, o); 256 threads, lane = (p, jg, h); n = h*7 + nn.
// out[b, j*16+p, o, n] = sum_{g,d} t4[b,g,o_src,n+d-2,p] * W2[g,d,j]
//   - [n==0] wconv[g,0,2,j]*t4[l=0]  - [n==13] wconv[g,2,0,j]*t4[l=13]
// LDS 17.4 KB -> 8 blocks/CU resident (epilogue staged in 2 chunks).
// ---------------------------------------------------------------------------
__global__ __launch_bounds__(256, 8) void conv_kernel(const float* __restrict__ t4,
                                                      const float* __restrict__ wconv,
                                                      float* __restrict__ out) {
    __shared__ __align__(16) float lds[4352];   // 17408 B
    float* t4s = lds;          // [8][16][LROW] = 2560
    float* w2s = lds + 2560;   // [8][5][32]    = 1280
    float* wcs = lds + 3840;   // [2][8][32]    =  512

    const int tid   = threadIdx.x;
    const int b     = blockIdx.x / NH;
    const int o     = blockIdx.x % NH;
    const int o_src = (o + NH - 1) % NH;

    // ---- stage t4 slice: 8 contiguous 896B chunks, coalesced ----
    const float* tsl = t4 + ((size_t)b * NG * HH + (size_t)o_src * NH) * NP;
#pragma unroll
    for (int r = 0; r < 7; r++) {                  // 1792 elements
        int idx = r * 256 + tid;
        int g   = idx / 224;                       // 14*16
        int rem = idx % 224;
        int l   = rem / 16;
        int p   = rem % 16;
        t4s[(g * 16 + p) * LROW + (l + 2)] = tsl[(size_t)g * HH * NP + l * 16 + p];
    }
    // zero pads: l2 in {0,1,16,17,18,19}
#pragma unroll
    for (int r = 0; r < 3; r++) {                  // 768 entries
        int idx = r * 256 + tid;
        int gp  = idx / 6;
        int s   = idx % 6;
        int l2  = (s < 2) ? s : (14 + s);
        t4s[gp * LROW + l2] = 0.f;
    }
    // W2[g][d][j] = sum_{i+k==d} wconv[g][i][k][j]
#pragma unroll
    for (int r = 0; r < 5; r++) {                  // 1280 entries
        int idx = r * 256 + tid;
        int g   = idx / 160;
        int di  = (idx / 32) % 5;
        int j   = idx % 32;
        int ilo = di > 2 ? di - 2 : 0;
        int ihi = di < 2 ? di : 2;
        float sum = 0.f;
        for (int i = ilo; i <= ihi; i++) sum += wconv[((g * 3 + i) * 3 + (di - i)) * 32 + j];
        w2s[idx] = sum;
    }
    // corrections: wcs[0][g][j]=wconv[g][0][2][j]; wcs[1][g][j]=wconv[g][2][0][j]
#pragma unroll
    for (int r = 0; r < 2; r++) {                  // 512 entries
        int idx = r * 256 + tid;
        int sel = idx / 256;
        int g   = (idx / 32) % 8;
        int j   = idx % 32;
        wcs[idx] = wconv[(g * 9 + (sel ? 6 : 2)) * 32 + j];
    }
    __syncthreads();

    const int p  = tid & 15;
    const int jg = (tid >> 4) & 7;
    const int h  = tid >> 7;

    float acc[7][4];
#pragma unroll
    for (int nn = 0; nn < 7; nn++) {
        acc[nn][0] = 0.f; acc[nn][1] = 0.f; acc[nn][2] = 0.f; acc[nn][3] = 0.f;
    }

    for (int g = 0; g < NG; g++) {
        float rowbuf[16];                          // row floats [4h .. 4h+15]
        const float* rp = &t4s[(g * NP + p) * LROW + 4 * h];
#pragma unroll
        for (int q = 0; q < 4; q++) {
            float4 v = *reinterpret_cast<const float4*>(rp + q * 4);
            rowbuf[q * 4 + 0] = v.x; rowbuf[q * 4 + 1] = v.y;
            rowbuf[q * 4 + 2] = v.z; rowbuf[q * 4 + 3] = v.w;
        }
#pragma unroll
        for (int di = 0; di < 5; di++) {
            float4 w = *reinterpret_cast<const float4*>(&w2s[(g * 5 + di) * 32 + jg * 4]);
#pragma unroll
            for (int nn = 0; nn < 7; nn++) {
                float rv = rowbuf[3 * h + nn + di];
                acc[nn][0] += rv * w.x;
                acc[nn][1] += rv * w.y;
                acc[nn][2] += rv * w.z;
                acc[nn][3] += rv * w.w;
            }
        }
        if (h == 0) {        // n==0: t4 l=0 -> rowbuf idx 2
            float4 c0 = *reinterpret_cast<const float4*>(&wcs[g * 32 + jg * 4]);
            float r0 = rowbuf[2];
            acc[0][0] -= r0 * c0.x; acc[0][1] -= r0 * c0.y;
            acc[0][2] -= r0 * c0.z; acc[0][3] -= r0 * c0.w;
        } else {             // n==13: t4 l=13 -> float idx 15 -> rowbuf idx 11
            float4 c1 = *reinterpret_cast<const float4*>(&wcs[256 + g * 32 + jg * 4]);
            float r13 = rowbuf[11];
            acc[6][0] -= r13 * c1.x; acc[6][1] -= r13 * c1.y;
            acc[6][2] -= r13 * c1.z; acc[6][3] -= r13 * c1.w;
        }
    }
    __syncthreads();   // t4s/weights dead; overlay lds as output stage

    // ---- epilogue: two 256-channel chunks through 15-stride LDS overlay ----
    float* ob = out + (size_t)b * 512 * HH + (size_t)o * NH;
#pragma unroll
    for (int ch = 0; ch < 2; ch++) {
        if ((jg >> 2) == ch) {
#pragma unroll
            for (int jj = 0; jj < 4; jj++) {
                int cl = (((jg & 3) * 4 + jj) * NP + p);   // channel - ch*256
#pragma unroll
                for (int nn = 0; nn < 7; nn++) lds[cl * 15 + h * 7 + nn] = acc[nn][jj];
            }
        }
        __syncthreads();
#pragma unroll
        for (int r = 0; r < 14; r++) {             // 3584 = 256*14
            int idx = r * 256 + tid;
            int cl  = idx / 14;
            int n   = idx % 14;
            ob[(size_t)(ch * 256 + cl) * HH + n] = lds[cl * 15 + n];
        }
        __syncthreads();
    }
}

extern "C" void kernel_launch(void* const* d_in, const int* in_sizes, int n_in,
                              void* d_out, int out_size, void* d_ws, size_t ws_size,
                              hipStream_t stream) {
    const float* x     = (const float*)d_in[0];
    const float* wconv = (const float*)d_in[1];
    const float* wmix  = (const float*)d_in[2];
    float* out = (float*)d_out;
    float* t4  = (float*)d_ws;   // 128*8*196*16 floats = 12.85 MB scratch

    mix_kernel<<<784, 256, 0, stream>>>(x, wmix, t4);
    conv_kernel<<<NB * NH, 256, 0, stream>>>(t4, wconv, out);
}

// Round 5
// 515.376 us; speedup vs baseline: 1.0442x; 1.0442x over previous
//
#include <hip/hip_runtime.h>

static constexpr int NB   = 128;
static constexpr int NCIN = 64;
static constexpr int NG   = 8;
static constexpr int NH   = 14;
static constexpr int NP   = 16;
static constexpr int HH   = NH * NH;   // 196
static constexpr int LROW = 20;        // padded t4 LDS row: l in [-2,17]

// ---------------------------------------------------------------------------
// Kernel 1: channel mix. t4[bg][s][p] = sum_cin x[b][cin][g][s] * wmix[cin][p]
// One spatial position per thread; wave = 64 consecutive s -> 256B coalesced
// loads. wmix staged in LDS: uniform-address ds_read_b128 broadcasts avoid
// the per-iteration s_load latency chain.
// ---------------------------------------------------------------------------
__global__ __launch_bounds__(256, 4) void mix_kernel(const float* __restrict__ x,
                                                     const float* __restrict__ wmix,
                                                     float* __restrict__ t4) {
    __shared__ __align__(16) float wmixs[NCIN * NP];   // 4 KB
#pragma unroll
    for (int r = 0; r < 4; r++) {
        int idx = r * 256 + threadIdx.x;
        wmixs[idx] = wmix[idx];
    }
    __syncthreads();

    int t  = blockIdx.x * 256 + threadIdx.x;   // enumerates (bg, s)
    int bg = t / HH;
    int s  = t % HH;

    float acc[NP];
#pragma unroll
    for (int p = 0; p < NP; p++) acc[p] = 0.f;

    const float* xb = x + (size_t)(bg >> 3) * (NCIN * NG * HH)
                        + (size_t)(bg & 7) * HH + s;

#pragma unroll 8
    for (int cin = 0; cin < NCIN; cin++) {
        float xv = xb[(size_t)cin * (NG * HH)];
        const float* wr = &wmixs[cin * NP];
#pragma unroll
        for (int q = 0; q < 4; q++) {
            float4 w = *reinterpret_cast<const float4*>(wr + q * 4);
            acc[q * 4 + 0] += xv * w.x;
            acc[q * 4 + 1] += xv * w.y;
            acc[q * 4 + 2] += xv * w.z;
            acc[q * 4 + 3] += xv * w.w;
        }
    }

    float* tb = t4 + (size_t)t * NP;
#pragma unroll
    for (int q = 0; q < 4; q++)
        *reinterpret_cast<float4*>(tb + q * 4) =
            make_float4(acc[q * 4 + 0], acc[q * 4 + 1], acc[q * 4 + 2], acc[q * 4 + 3]);
}

// ---------------------------------------------------------------------------
// Kernel 2: 5-tap conv along l + boundary corrections + roll + transpose.
// block = (b, o); 256 threads, lane = (p, jg, h); n = h*7 + nn.
// out[b, j*16+p, o, n] = sum_{g,d} t4[b,g,o_src,n+d-2,p] * W2[g,d,j]
//   - [n==0] wconv[g,0,2,j]*t4[l=0]  - [n==13] wconv[g,2,0,j]*t4[l=13]
// launch_bounds (256,4): cap 128 VGPR -- R2's (256,8) forced 64-VGPR budget
// and spilled the accumulators (1.4 GB scratch traffic). Residency: LDS
// 17.4 KB and ~70 VGPR both give ~7 blocks/CU.
// ---------------------------------------------------------------------------
__global__ __launch_bounds__(256, 4) void conv_kernel(const float* __restrict__ t4,
                                                      const float* __restrict__ wconv,
                                                      float* __restrict__ out) {
    __shared__ __align__(16) float lds[4352];   // 17408 B
    float* t4s = lds;          // [8][16][LROW] = 2560
    float* w2s = lds + 2560;   // [8][5][32]    = 1280
    float* wcs = lds + 3840;   // [2][8][32]    =  512

    const int tid   = threadIdx.x;
    const int b     = blockIdx.x / NH;
    const int o     = blockIdx.x % NH;
    const int o_src = (o + NH - 1) % NH;

    // ---- stage t4 slice (coalesced read, transposed LDS write) ----
    const float* tsl = t4 + ((size_t)b * NG * HH + (size_t)o_src * NH) * NP;
#pragma unroll
    for (int r = 0; r < 7; r++) {                  // 1792 elements
        int idx = r * 256 + tid;
        int g   = idx / 224;                       // 14*16
        int rem = idx % 224;
        int l   = rem / 16;
        int p   = rem % 16;
        t4s[(g * 16 + p) * LROW + (l + 2)] = tsl[(size_t)g * HH * NP + l * 16 + p];
    }
    // zero pads: l2 in {0,1,16,17,18,19}
#pragma unroll
    for (int r = 0; r < 3; r++) {                  // 768 entries
        int idx = r * 256 + tid;
        int gp  = idx / 6;
        int s   = idx % 6;
        int l2  = (s < 2) ? s : (14 + s);
        t4s[gp * LROW + l2] = 0.f;
    }
    // W2[g][d][j] = sum_{i+k==d} wconv[g][i][k][j]
#pragma unroll
    for (int r = 0; r < 5; r++) {                  // 1280 entries
        int idx = r * 256 + tid;
        int g   = idx / 160;
        int di  = (idx / 32) % 5;
        int j   = idx % 32;
        int ilo = di > 2 ? di - 2 : 0;
        int ihi = di < 2 ? di : 2;
        float sum = 0.f;
        for (int i = ilo; i <= ihi; i++) sum += wconv[((g * 3 + i) * 3 + (di - i)) * 32 + j];
        w2s[idx] = sum;
    }
    // corrections: wcs[0][g][j]=wconv[g][0][2][j]; wcs[1][g][j]=wconv[g][2][0][j]
#pragma unroll
    for (int r = 0; r < 2; r++) {                  // 512 entries
        int idx = r * 256 + tid;
        int sel = idx / 256;
        int g   = (idx / 32) % 8;
        int j   = idx % 32;
        wcs[idx] = wconv[(g * 9 + (sel ? 6 : 2)) * 32 + j];
    }
    __syncthreads();

    const int p  = tid & 15;
    const int jg = (tid >> 4) & 7;
    const int h  = tid >> 7;

    float acc[7][4];
#pragma unroll
    for (int nn = 0; nn < 7; nn++) {
        acc[nn][0] = 0.f; acc[nn][1] = 0.f; acc[nn][2] = 0.f; acc[nn][3] = 0.f;
    }

    for (int g = 0; g < NG; g++) {
        float rowbuf[16];                          // row floats [4h .. 4h+15]
        const float* rp = &t4s[(g * NP + p) * LROW + 4 * h];
#pragma unroll
        for (int q = 0; q < 4; q++) {
            float4 v = *reinterpret_cast<const float4*>(rp + q * 4);
            rowbuf[q * 4 + 0] = v.x; rowbuf[q * 4 + 1] = v.y;
            rowbuf[q * 4 + 2] = v.z; rowbuf[q * 4 + 3] = v.w;
        }
#pragma unroll
        for (int di = 0; di < 5; di++) {
            float4 w = *reinterpret_cast<const float4*>(&w2s[(g * 5 + di) * 32 + jg * 4]);
#pragma unroll
            for (int nn = 0; nn < 7; nn++) {
                float rv = rowbuf[3 * h + nn + di];
                acc[nn][0] += rv * w.x;
                acc[nn][1] += rv * w.y;
                acc[nn][2] += rv * w.z;
                acc[nn][3] += rv * w.w;
            }
        }
        if (h == 0) {        // n==0: t4 l=0 -> rowbuf idx 2
            float4 c0 = *reinterpret_cast<const float4*>(&wcs[g * 32 + jg * 4]);
            float r0 = rowbuf[2];
            acc[0][0] -= r0 * c0.x; acc[0][1] -= r0 * c0.y;
            acc[0][2] -= r0 * c0.z; acc[0][3] -= r0 * c0.w;
        } else {             // n==13: t4 l=13 -> float idx 15 -> rowbuf idx 11
            float4 c1 = *reinterpret_cast<const float4*>(&wcs[256 + g * 32 + jg * 4]);
            float r13 = rowbuf[11];
            acc[6][0] -= r13 * c1.x; acc[6][1] -= r13 * c1.y;
            acc[6][2] -= r13 * c1.z; acc[6][3] -= r13 * c1.w;
        }
    }
    __syncthreads();   // t4s/weights dead; overlay lds as output stage

    // ---- epilogue: two 256-channel chunks through 15-stride LDS overlay ----
    float* ob = out + (size_t)b * 512 * HH + (size_t)o * NH;
#pragma unroll
    for (int ch = 0; ch < 2; ch++) {
        if ((jg >> 2) == ch) {
#pragma unroll
            for (int jj = 0; jj < 4; jj++) {
                int cl = (((jg & 3) * 4 + jj) * NP + p);   // channel - ch*256
#pragma unroll
                for (int nn = 0; nn < 7; nn++) lds[cl * 15 + h * 7 + nn] = acc[nn][jj];
            }
        }
        __syncthreads();
#pragma unroll
        for (int r = 0; r < 14; r++) {             // 3584 = 256*14
            int idx = r * 256 + tid;
            int cl  = idx / 14;
            int n   = idx % 14;
            ob[(size_t)(ch * 256 + cl) * HH + n] = lds[cl * 15 + n];
        }
        __syncthreads();
    }
}

extern "C" void kernel_launch(void* const* d_in, const int* in_sizes, int n_in,
                              void* d_out, int out_size, void* d_ws, size_t ws_size,
                              hipStream_t stream) {
    const float* x     = (const float*)d_in[0];
    const float* wconv = (const float*)d_in[1];
    const float* wmix  = (const float*)d_in[2];
    float* out = (float*)d_out;
    float* t4  = (float*)d_ws;   // 128*8*196*16 floats = 12.85 MB scratch

    mix_kernel<<<784, 256, 0, stream>>>(x, wmix, t4);
    conv_kernel<<<NB * NH, 256, 0, stream>>>(t4, wconv, out);
}